// Round 11
// baseline (116.304 us; speedup 1.0000x reference)
//
#include <hip/hip_runtime.h>

// VQVAE quantize.  x: [8,64,32,32] fp32, codebook: [8192,64] fp32.
// d_out (fp32, concat): [0,524288) quant_out | [524288] commit_loss |
//                       [524289] codebook_loss | [524290,532482) indices
//
// argmin via bf16x3 emulated-fp32 MFMA GEMM, now on 32x32x16 (2495 TF
// measured ceiling vs 2075 for 16x16x32; floor 24.8 -> 20.7 us, and
// half the MFMA instructions per MAC).
//   v = h + m + l (3 bf16, exact to ~2^-27); dot = hh+hm+mh+hl+lh+mm
//   score = dot - 0.5*e2[k]  (argmax score == argmin d2; verified absmax 0)
//
// R10 lesson: plateau is per-wave issue economics, not residency and not
// L2 requests (R9 ruled that out). Bigger MFMA + fewer instructions is
// the remaining lever. R7/R9: B deduped through LDS. R6: never tighten
// __launch_bounds__ below natural VGPR alloc.

#define N_PTS   8192
#define K_CODES 8192
#define C_DIM   64
#define HWSZ    1024
#define QOUT_N  524288
#define SPLITS  16            // codes per split = 512 = 8 chunks of 64

// ---- workspace layout (bytes) ----
#define WS_XS    0            // u16 [3][8][8192][8]  = 3145728
#define WS_CBS   3145728      // u16 [3*8][8192][8]   = 3145728
#define WS_E2H   6291456      // float [8192]         = 32768
#define WS_PACK  6324224      // u64 [16][8192]       = 1048576
#define WS_PART  7372800      // float [512]

typedef __attribute__((ext_vector_type(8)))  short short8;
typedef __attribute__((ext_vector_type(16))) float floatx16;

__device__ __forceinline__ unsigned short bf16_rne(float f) {
    unsigned u = __float_as_uint(f);
    return (unsigned short)((u + 0x7FFFu + ((u >> 16) & 1u)) >> 16);
}
__device__ __forceinline__ float bf16_val(unsigned short h) {
    return __uint_as_float(((unsigned)h) << 16);
}
__device__ __forceinline__ void split3(float v, unsigned short& h,
                                       unsigned short& m, unsigned short& l) {
    h = bf16_rne(v);
    float r1 = v - bf16_val(h);
    m = bf16_rne(r1);
    float r2 = r1 - bf16_val(m);
    l = bf16_rne(r2);
}
__device__ __forceinline__ void cp16(const void* g, void* l) {
    __builtin_amdgcn_global_load_lds(
        (const __attribute__((address_space(1))) void*)g,
        (__attribute__((address_space(3))) void*)l, 16, 0, 0);
}
__device__ __forceinline__ void cp4(const void* g, void* l) {
    __builtin_amdgcn_global_load_lds(
        (const __attribute__((address_space(1))) void*)g,
        (__attribute__((address_space(3))) void*)l, 4, 0, 0);
}

// ============================================================
// Kernel A: prep (no LDS, all coalesced). Unchanged layout:
// plane [p*8+g][n][8]: 16B per (point|code, c-octet g). For the
// 32x32x16 MFMA, kstep s + lane-half h consume octet g = s*2+h.
// ============================================================
__global__ __launch_bounds__(256)
void vq_prep_kernel(const float* __restrict__ x,
                    const float* __restrict__ cb,
                    unsigned short* __restrict__ xS,
                    unsigned short* __restrict__ cbS,
                    float* __restrict__ e2h)
{
    const int bx  = blockIdx.x;
    const int tid = threadIdx.x;

    if (bx < 32) {                           // ---- cb split + e2h ----
        const int k = bx * 256 + tid;
        const float* row = cb + k * C_DIM;
        float s = 0.0f;
        #pragma unroll
        for (int g = 0; g < 8; ++g) {
            float4 a = *(const float4*)(row + g * 8);
            float4 b = *(const float4*)(row + g * 8 + 4);
            float vv[8] = {a.x, a.y, a.z, a.w, b.x, b.y, b.z, b.w};
            unsigned short h8[8], m8[8], l8[8];
            #pragma unroll
            for (int j = 0; j < 8; ++j) {
                s = fmaf(vv[j], vv[j], s);
                split3(vv[j], h8[j], m8[j], l8[j]);
            }
            *(uint4*)(cbS + ((size_t)(0 * 8 + g) * 8192 + k) * 8) = *(const uint4*)h8;
            *(uint4*)(cbS + ((size_t)(1 * 8 + g) * 8192 + k) * 8) = *(const uint4*)m8;
            *(uint4*)(cbS + ((size_t)(2 * 8 + g) * 8192 + k) * 8) = *(const uint4*)l8;
        }
        e2h[k] = 0.5f * s;
    } else {                                 // ---- x split ----
        const int u = bx - 32;               // 0..63
        const int b = u >> 3, g = u & 7;
        const float* xb = x + (size_t)(b * C_DIM + g * 8) * HWSZ;
        float v[4][8];                       // [j][cq]
        #pragma unroll
        for (int cq = 0; cq < 8; ++cq) {
            float4 t4 = *(const float4*)(xb + cq * HWSZ + tid * 4);
            v[0][cq] = t4.x; v[1][cq] = t4.y; v[2][cq] = t4.z; v[3][cq] = t4.w;
        }
        #pragma unroll
        for (int j = 0; j < 4; ++j) {
            unsigned short h8[8], m8[8], l8[8];
            #pragma unroll
            for (int cq = 0; cq < 8; ++cq)
                split3(v[j][cq], h8[cq], m8[cq], l8[cq]);
            const size_t n = (size_t)b * 1024 + tid * 4 + j;
            *(uint4*)(xS + ((size_t)(0 * 8 + g) * 8192 + n) * 8) = *(const uint4*)h8;
            *(uint4*)(xS + ((size_t)(1 * 8 + g) * 8192 + n) * 8) = *(const uint4*)m8;
            *(uint4*)(xS + ((size_t)(2 * 8 + g) * 8192 + n) * 8) = *(const uint4*)l8;
        }
    }
}

// ============================================================
// Kernel B: argmin via 32x32x16 MFMA. grid (64 m-blocks, 16
// splits) x 256 threads. Wave owns one 32-point m-tile: A-frags
// af[p][s] in 48 VGPRs. Per 64-code chunk staged into LDS
// (double-buffered, 1 barrier/chunk): 2 n-tiles of 32 codes,
// each 24 MFMAs in two accumulator chains (accA: hh,mh,lh;
// accB: hm,hl,mm), score = accA+accB (acc init -e2h / 0).
// Layouts: C/D col=lane&31, row=(reg&3)+8*(reg>>2)+4*(lane>>5)
// [verified m74/m101]; A m=lane&31, k=(lane>>5)*8+j; B n=lane&31,
// k=(lane>>5)*8+j  (same half*8+j grouping as the verified 16x16
// quad*8+j pattern). Final: 5-step __shfl_xor u64 min per half.
// ============================================================
#define SEG_SHORTS 512        // 64 codes * 8 shorts per (p,g) segment
#define BUF_SHORTS 12416      // 24 segs * 512 + 128 shorts (e2 slice 64 floats)

__global__ __launch_bounds__(256, 2)
void vq_argmin_kernel(const unsigned short* __restrict__ xS,
                      const unsigned short* __restrict__ cbS,
                      const float* __restrict__ e2h,
                      unsigned long long* __restrict__ packedS)
{
    __shared__ __align__(16) unsigned short sBuf[2][BUF_SHORTS];  // 49664 B

    const int tid   = threadIdx.x;
    const int lane  = tid & 63;
    const int w     = tid >> 6;          // 0..3
    const int l31   = lane & 31;
    const int half  = lane >> 5;
    const int mb    = blockIdx.x;        // 0..63
    const int split = blockIdx.y;        // 0..15
    const int m0    = mb * 128 + w * 32;
    const int nb0   = split * 512;

    // A fragments: 3 planes x 4 ksteps (48 VGPRs). pt = m0 + l31.
    short8 af[3][4];
    {
        const int pt = m0 + l31;
        #pragma unroll
        for (int p = 0; p < 3; ++p)
            #pragma unroll
            for (int s = 0; s < 4; ++s) {
                int g = s * 2 + half;
                af[p][s] = *(const short8*)(xS + ((size_t)(p * 8 + g) * 8192 + pt) * 8);
            }
    }

    float bestv[16];
    int   besti[16];
    #pragma unroll
    for (int r = 0; r < 16; ++r) {
        bestv[r] = __uint_as_float(0xFF800000u);   // -inf
        besti[r] = 0;
    }

    // async stage of one 64-code chunk: 24 segs x 1KB + e2 slice
    auto stage = [&](int k0, int buf) {
        unsigned short* dst = &sBuf[buf][0];
        #pragma unroll
        for (int i = 0; i < 6; ++i) {
            int f   = tid + i * 256;         // 0..1535
            int seg = f >> 6;                // wave-uniform
            int l   = f & 63;
            cp16(cbS + ((size_t)seg * 8192 + k0 + l) * 8,
                 dst + seg * SEG_SHORTS + l * 8);
        }
        if (tid < 64)
            cp4(e2h + k0 + tid, (float*)(dst + 24 * SEG_SHORTS) + tid);
    };

    stage(nb0, 0);
    __syncthreads();                          // chunk 0 staged

    for (int ch = 0; ch < 8; ++ch) {
        if (ch + 1 < 8) stage(nb0 + (ch + 1) * 64, (ch + 1) & 1);
        const unsigned short* bsrc = &sBuf[ch & 1][0];
        const float* e2s = (const float*)(bsrc + 24 * SEG_SHORTS);

        #pragma unroll
        for (int ntl = 0; ntl < 2; ++ntl) {
            const int lc   = ntl * 32 + l31;            // code within chunk
            const int code = nb0 + ch * 64 + lc;
            const float me2 = -e2s[lc];

            floatx16 accA, accB;
            #pragma unroll
            for (int r = 0; r < 16; ++r) { accA[r] = me2; accB[r] = 0.0f; }

            #pragma unroll
            for (int s = 0; s < 4; ++s) {
                const int g = s * 2 + half;
                short8 b0 = *(const short8*)(bsrc + (0 * 8 + g) * SEG_SHORTS + lc * 8);
                short8 b1 = *(const short8*)(bsrc + (1 * 8 + g) * SEG_SHORTS + lc * 8);
                short8 b2 = *(const short8*)(bsrc + (2 * 8 + g) * SEG_SHORTS + lc * 8);
                accA = __builtin_amdgcn_mfma_f32_32x32x16_bf16(af[0][s], b0, accA, 0, 0, 0); // hh
                accB = __builtin_amdgcn_mfma_f32_32x32x16_bf16(af[0][s], b1, accB, 0, 0, 0); // hm
                accA = __builtin_amdgcn_mfma_f32_32x32x16_bf16(af[1][s], b0, accA, 0, 0, 0); // mh
                accB = __builtin_amdgcn_mfma_f32_32x32x16_bf16(af[0][s], b2, accB, 0, 0, 0); // hl
                accA = __builtin_amdgcn_mfma_f32_32x32x16_bf16(af[2][s], b0, accA, 0, 0, 0); // lh
                accB = __builtin_amdgcn_mfma_f32_32x32x16_bf16(af[1][s], b1, accB, 0, 0, 0); // mm
            }

            #pragma unroll
            for (int r = 0; r < 16; ++r) {
                float sc = accA[r] + accB[r];
                bool gt = sc > bestv[r];           // strict: earlier code wins ties
                bestv[r] = gt ? sc   : bestv[r];
                besti[r] = gt ? code : besti[r];
            }
        }
        __syncthreads();        // reads of ch done + prefetch ch+1 landed
    }

    // final reduce: for each acc row r, u64-min across the 32 code-cols
    // of this half (xor masks 1..16 stay within the 32-lane half).
    // Lane l31 == r owns row r and writes point m0 + row(r, half).
    unsigned long long own = 0;
    #pragma unroll
    for (int r = 0; r < 16; ++r) {
        unsigned u = __float_as_uint(-bestv[r]);   // key ascending
        u = ((int)u < 0) ? ~u : (u | 0x80000000u);
        unsigned long long p = ((unsigned long long)u << 32) | (unsigned)besti[r];
        #pragma unroll
        for (int msk = 1; msk < 32; msk <<= 1) {
            unsigned long long q = __shfl_xor(p, msk, 64);
            p = (q < p) ? q : p;
        }
        own = (l31 == r) ? p : own;
    }
    if (l31 < 16) {
        const int row = (l31 & 3) + 8 * (l31 >> 2) + 4 * half;
        packedS[(size_t)split * N_PTS + m0 + row] = own;
    }
}

// ============================================================
// Kernel C: gather. 128 blocks x 256; block owns 64 points.
// Wave 0 reduces the 16 split slots once per point, broadcasts
// idx via LDS + writes indices. All 4 waves then handle one
// 16-channel quarter each (fully coalesced x/out access).
// ============================================================
__global__ __launch_bounds__(256)
void vq_gather_kernel(const float* __restrict__ x,
                      const float* __restrict__ cb,
                      const unsigned long long* __restrict__ packedS,
                      float* __restrict__ out,
                      float* __restrict__ part)
{
    __shared__ int sidx[64];
    const int tid  = threadIdx.x;
    const int lane = tid & 63;
    const int qd   = tid >> 6;          // wave id = channel quarter
    const int n0   = blockIdx.x * 64;
    const int n    = n0 + lane;

    if (qd == 0) {
        unsigned long long v = packedS[n];
        #pragma unroll
        for (int s = 1; s < SPLITS; ++s) {
            unsigned long long q = packedS[(size_t)s * N_PTS + n];
            v = (q < v) ? q : v;
        }
        int idx = (int)(v & 0xFFFFFFFFull);
        sidx[lane] = idx;
        out[QOUT_N + 2 + n] = (float)idx;
    }
    __syncthreads();

    const int idx = sidx[lane];
    const int c0  = qd * 16;
    const int b   = n >> 10;
    const int hw  = n & 1023;
    const float* xb = x   + (size_t)b * (C_DIM * HWSZ) + hw;
    float*       ob = out + (size_t)b * (C_DIM * HWSZ) + hw;

    float s = 0.0f;
    #pragma unroll
    for (int c4 = 0; c4 < 4; ++c4) {
        float4 q = *(const float4*)(cb + (size_t)idx * C_DIM + c0 + c4 * 4);
        float qa[4] = {q.x, q.y, q.z, q.w};
        #pragma unroll
        for (int j = 0; j < 4; ++j) {
            int c = c0 + c4 * 4 + j;
            float xv = xb[c * HWSZ];
            float d  = qa[j] - xv;          // quant - x (reference rounding)
            s = fmaf(d, d, s);
            ob[c * HWSZ] = xv + d;          // straight-through: x + (q - x)
        }
    }

    #pragma unroll
    for (int off = 32; off > 0; off >>= 1) s += __shfl_down(s, off, 64);
    if (lane == 0) part[blockIdx.x * 4 + qd] = s;
}

// ============================================================
// Kernel D: final loss reduction (512 partials -> 2 scalars).
// ============================================================
__global__ __launch_bounds__(256)
void vq_final_kernel(const float* __restrict__ part, float* __restrict__ out)
{
    __shared__ float w[4];
    float s = part[threadIdx.x] + part[threadIdx.x + 256];
    #pragma unroll
    for (int off = 32; off > 0; off >>= 1) s += __shfl_down(s, off, 64);
    if ((threadIdx.x & 63) == 0) w[threadIdx.x >> 6] = s;
    __syncthreads();
    if (threadIdx.x == 0) {
        float m = (w[0] + w[1] + w[2] + w[3]) * (1.0f / (float)QOUT_N);
        out[QOUT_N]     = m;   // commitment_loss
        out[QOUT_N + 1] = m;   // codebook_loss
    }
}

extern "C" void kernel_launch(void* const* d_in, const int* in_sizes, int n_in,
                              void* d_out, int out_size, void* d_ws, size_t ws_size,
                              hipStream_t stream)
{
    const float* x  = (const float*)d_in[0];   // [8,64,32,32]
    const float* cb = (const float*)d_in[1];   // [8192,64]
    float* out = (float*)d_out;
    char*  ws  = (char*)d_ws;
    (void)ws_size;

    unsigned short* xS  = (unsigned short*)(ws + WS_XS);
    unsigned short* cbS = (unsigned short*)(ws + WS_CBS);
    float* e2h = (float*)(ws + WS_E2H);
    unsigned long long* packedS = (unsigned long long*)(ws + WS_PACK);
    float* part = (float*)(ws + WS_PART);

    vq_prep_kernel<<<96, 256, 0, stream>>>(x, cb, xS, cbS, e2h);
    vq_argmin_kernel<<<dim3(64, SPLITS), 256, 0, stream>>>(xS, cbS, e2h, packedS);
    vq_gather_kernel<<<128, 256, 0, stream>>>(x, cb, packedS, out, part);
    vq_final_kernel<<<1, 256, 0, stream>>>(part, out);
}

// Round 12
// 94.199 us; speedup vs baseline: 1.2347x; 1.2347x over previous
//
#include <hip/hip_runtime.h>

// VQVAE quantize.  x: [8,64,32,32] fp32, codebook: [8192,64] fp32.
// d_out (fp32, concat): [0,524288) quant_out | [524288] commit_loss |
//                       [524289] codebook_loss | [524290,532482) indices
//
// argmin via fp16x2 emulated-fp32 MFMA GEMM (3 terms):
//   v = h + m (2 fp16, exact to ~|v|*2^-23); dot ~= hh + hm + mh
//   (dropped mm term ~5e-7; total err ~2e-6 — same scale as the bf16x3
//    path that measured absmax 0 in R4-R11)
//   score = dot - 0.5*e2[k]  (argmax score == argmin d2)
//
// R11 lesson: the 6-term bf16x3 MFMA work was half the runtime; halve
// the math (fp16x2, 3 terms) not the plumbing. Structure = R9 (best
// measured): LDS-staged 64-code chunks, single buffer, shuffle reduce.
// R7: B deduped through LDS. R6: no launch_bounds tighter than natural.

#define N_PTS   8192
#define K_CODES 8192
#define C_DIM   64
#define HWSZ    1024
#define QOUT_N  524288
#define SPLITS  32            // codes per split = 256 = 4 chunks of 64

// ---- workspace layout (bytes) ----
#define WS_XS    0            // u16 [2][8][8192][8]  = 2097152
#define WS_CBS   2097152      // u16 [2*8][8192][8]   = 2097152
#define WS_E2H   4194304      // float [8192]         = 32768
#define WS_PACK  4227072      // u64 [32][8192]       = 2097152
#define WS_PART  6324224      // float [512]

typedef __attribute__((ext_vector_type(8))) short    short8;
typedef __attribute__((ext_vector_type(8))) _Float16 half8;
typedef __attribute__((ext_vector_type(4))) float    floatx4;

__device__ __forceinline__ half8 as_h8(short8 v) {
    return __builtin_bit_cast(half8, v);
}
__device__ __forceinline__ void split2(float v, unsigned short& h,
                                       unsigned short& m) {
    _Float16 hh = (_Float16)v;                     // RNE
    float r = v - (float)hh;
    _Float16 mm = (_Float16)r;
    h = __builtin_bit_cast(unsigned short, hh);
    m = __builtin_bit_cast(unsigned short, mm);
}
__device__ __forceinline__ void cp16(const void* g, void* l) {
    __builtin_amdgcn_global_load_lds(
        (const __attribute__((address_space(1))) void*)g,
        (__attribute__((address_space(3))) void*)l, 16, 0, 0);
}
__device__ __forceinline__ void cp4(const void* g, void* l) {
    __builtin_amdgcn_global_load_lds(
        (const __attribute__((address_space(1))) void*)g,
        (__attribute__((address_space(3))) void*)l, 4, 0, 0);
}

// ============================================================
// Kernel A: prep (no LDS, all coalesced).
//  blocks 0..31  : cb split + e2h (1 row/thread).
//  blocks 32..95 : x split, block=(b,g), 4 points/thread.
// Plane layout [p*8+g][n][8], p in {0=h,1=m}: 16B per
// (point|code, c-octet g) == one MFMA fragment k-group.
// ============================================================
__global__ __launch_bounds__(256)
void vq_prep_kernel(const float* __restrict__ x,
                    const float* __restrict__ cb,
                    unsigned short* __restrict__ xS,
                    unsigned short* __restrict__ cbS,
                    float* __restrict__ e2h)
{
    const int bx  = blockIdx.x;
    const int tid = threadIdx.x;

    if (bx < 32) {                           // ---- cb split + e2h ----
        const int k = bx * 256 + tid;
        const float* row = cb + k * C_DIM;
        float s = 0.0f;
        #pragma unroll
        for (int g = 0; g < 8; ++g) {
            float4 a = *(const float4*)(row + g * 8);
            float4 b = *(const float4*)(row + g * 8 + 4);
            float vv[8] = {a.x, a.y, a.z, a.w, b.x, b.y, b.z, b.w};
            unsigned short h8[8], m8[8];
            #pragma unroll
            for (int j = 0; j < 8; ++j) {
                s = fmaf(vv[j], vv[j], s);
                split2(vv[j], h8[j], m8[j]);
            }
            *(uint4*)(cbS + ((size_t)(0 * 8 + g) * 8192 + k) * 8) = *(const uint4*)h8;
            *(uint4*)(cbS + ((size_t)(1 * 8 + g) * 8192 + k) * 8) = *(const uint4*)m8;
        }
        e2h[k] = 0.5f * s;
    } else {                                 // ---- x split ----
        const int u = bx - 32;               // 0..63
        const int b = u >> 3, g = u & 7;
        const float* xb = x + (size_t)(b * C_DIM + g * 8) * HWSZ;
        float v[4][8];                       // [j][cq]
        #pragma unroll
        for (int cq = 0; cq < 8; ++cq) {
            float4 t4 = *(const float4*)(xb + cq * HWSZ + tid * 4);
            v[0][cq] = t4.x; v[1][cq] = t4.y; v[2][cq] = t4.z; v[3][cq] = t4.w;
        }
        #pragma unroll
        for (int j = 0; j < 4; ++j) {
            unsigned short h8[8], m8[8];
            #pragma unroll
            for (int cq = 0; cq < 8; ++cq)
                split2(v[j][cq], h8[cq], m8[cq]);
            const size_t n = (size_t)b * 1024 + tid * 4 + j;
            *(uint4*)(xS + ((size_t)(0 * 8 + g) * 8192 + n) * 8) = *(const uint4*)h8;
            *(uint4*)(xS + ((size_t)(1 * 8 + g) * 8192 + n) * 8) = *(const uint4*)m8;
        }
    }
}

// ============================================================
// Kernel B: argmin via 16x16x32 f16 MFMA. grid (32 m-blocks,
// 32 splits) x 256 threads; LDS 16.6 KB single buffer.
// Wave owns 64 points (4 tiles of 16); A-frags in regs (64 VGPR,
// 2 planes x 2 ksteps x 4 tiles). Per 64-code chunk: async stage,
// sync, 4 tiles x 24 MFMA (3 terms: hh,hm,mh; 4 parallel per-t
// chains), sync. Final reduce via __shfl_xor u64 min.
// Layouts (verified m89/m91/m120): A[m=lane&15][k=quad*8+j],
// B[k=quad*8+j][n=lane&15], C: col=lane&15, row=quad*4+reg.
// ============================================================
#define SEG_SHORTS 512        // 64 codes * 8 shorts per (p,g) segment
#define NSEGS      16         // 2 planes x 8 octets
#define BUF_SHORTS 8320       // 16*512 + 128 (e2 slice: 64 floats)

__device__ __forceinline__ void computeTile(const half8 af[4][2][2],
                                            const unsigned short* __restrict__ bsrc,
                                            int tl, int quad, int col, int code,
                                            float bestv[4][4], int besti[4][4])
{
    half8 bf[2][2];
    #pragma unroll
    for (int p = 0; p < 2; ++p)
        #pragma unroll
        for (int s = 0; s < 2; ++s) {
            int seg = p * 8 + s * 4 + quad;
            bf[p][s] = as_h8(*(const short8*)(bsrc + seg * SEG_SHORTS + (tl * 16 + col) * 8));
        }
    float me2 = -((const float*)(bsrc + NSEGS * SEG_SHORTS))[tl * 16 + col];

    floatx4 acc[4];
    #pragma unroll
    for (int t = 0; t < 4; ++t) acc[t] = (floatx4){me2, me2, me2, me2};

    #pragma unroll
    for (int s = 0; s < 2; ++s) {
        #pragma unroll
        for (int t = 0; t < 4; ++t)
            acc[t] = __builtin_amdgcn_mfma_f32_16x16x32_f16(af[t][0][s], bf[0][s], acc[t], 0, 0, 0); // hh
        #pragma unroll
        for (int t = 0; t < 4; ++t)
            acc[t] = __builtin_amdgcn_mfma_f32_16x16x32_f16(af[t][0][s], bf[1][s], acc[t], 0, 0, 0); // hm
        #pragma unroll
        for (int t = 0; t < 4; ++t)
            acc[t] = __builtin_amdgcn_mfma_f32_16x16x32_f16(af[t][1][s], bf[0][s], acc[t], 0, 0, 0); // mh
    }

    #pragma unroll
    for (int t = 0; t < 4; ++t)
        #pragma unroll
        for (int r = 0; r < 4; ++r) {
            float sc = acc[t][r];
            bool gt = sc > bestv[t][r];        // strict: earlier code wins ties
            bestv[t][r] = gt ? sc   : bestv[t][r];
            besti[t][r] = gt ? code : besti[t][r];
        }
}

__global__ __launch_bounds__(256, 2)
void vq_argmin_kernel(const unsigned short* __restrict__ xS,
                      const unsigned short* __restrict__ cbS,
                      const float* __restrict__ e2h,
                      unsigned long long* __restrict__ packedS)
{
    __shared__ __align__(16) unsigned short sBuf[BUF_SHORTS];   // 16640 B

    const int tid   = threadIdx.x;
    const int lane  = tid & 63;
    const int w     = tid >> 6;
    const int col   = lane & 15;
    const int quad  = lane >> 4;
    const int mb    = blockIdx.x;
    const int split = blockIdx.y;
    const int m0    = mb * 256 + w * 64;
    const int nb0   = split * 256;

    // A fragments: 4 tiles x 2 planes x 2 ksteps (64 VGPRs)
    half8 af[4][2][2];
    #pragma unroll
    for (int t = 0; t < 4; ++t) {
        int pt = m0 + t * 16 + col;
        #pragma unroll
        for (int p = 0; p < 2; ++p)
            #pragma unroll
            for (int s = 0; s < 2; ++s) {
                int g = s * 4 + quad;
                af[t][p][s] = as_h8(*(const short8*)(xS + ((size_t)(p * 8 + g) * 8192 + pt) * 8));
            }
    }

    float bestv[4][4];
    int   besti[4][4];
    #pragma unroll
    for (int t = 0; t < 4; ++t)
        #pragma unroll
        for (int r = 0; r < 4; ++r) {
            bestv[t][r] = __uint_as_float(0xFF800000u);  // -inf
            besti[t][r] = 0;
        }

    // async stage of one 64-code chunk: 16 segs x 1KB + e2 slice
    auto stage = [&](int k0) {
        #pragma unroll
        for (int i = 0; i < 4; ++i) {
            int f   = tid + i * 256;         // 0..1023
            int seg = f >> 6;                // wave-uniform
            int l   = f & 63;                // = lane
            cp16(cbS + ((size_t)seg * 8192 + k0 + l) * 8,
                 sBuf + seg * SEG_SHORTS + l * 8);
        }
        if (tid < 64)
            cp4(e2h + k0 + tid, (float*)(sBuf + NSEGS * SEG_SHORTS) + tid);
    };

    stage(nb0);
    __syncthreads();                          // chunk 0 staged

    for (int ch = 0; ch < 4; ++ch) {
        #pragma unroll
        for (int tl = 0; tl < 4; ++tl)
            computeTile(af, sBuf, tl, quad, col,
                        nb0 + ch * 64 + tl * 16 + col, bestv, besti);
        if (ch + 1 < 4) {
            __syncthreads();                  // all reads of sBuf done
            stage(nb0 + (ch + 1) * 64);
            __syncthreads();                  // next chunk staged
        }
    }

    // final reduce over the 16 col-candidates per point, in-register:
    // per (t,r), u64-min across the 16 col lanes of each quad group
    // (xor masks 1,2,4,8 stay within the group). Lane with col==t*4+r
    // owns pair (t,r) and writes point m0 + t*16 + quad*4 + r.
    unsigned long long own = 0;
    #pragma unroll
    for (int t = 0; t < 4; ++t)
        #pragma unroll
        for (int r = 0; r < 4; ++r) {
            unsigned u = __float_as_uint(-bestv[t][r]);   // key ascending
            u = ((int)u < 0) ? ~u : (u | 0x80000000u);
            unsigned long long p = ((unsigned long long)u << 32) | (unsigned)besti[t][r];
            #pragma unroll
            for (int msk = 1; msk < 16; msk <<= 1) {
                unsigned long long q = __shfl_xor(p, msk, 64);
                p = (q < p) ? q : p;
            }
            own = (col == t * 4 + r) ? p : own;
        }
    const int mpt = m0 + (col >> 2) * 16 + quad * 4 + (col & 3);
    packedS[(size_t)split * N_PTS + mpt] = own;
}

// ============================================================
// Kernel C: gather. 128 blocks x 256; block owns 64 points.
// Wave 0 reduces the 32 split slots once per point, broadcasts
// idx via LDS + writes indices. All 4 waves then handle one
// 16-channel quarter each (fully coalesced x/out access).
// ============================================================
__global__ __launch_bounds__(256)
void vq_gather_kernel(const float* __restrict__ x,
                      const float* __restrict__ cb,
                      const unsigned long long* __restrict__ packedS,
                      float* __restrict__ out,
                      float* __restrict__ part)
{
    __shared__ int sidx[64];
    const int tid  = threadIdx.x;
    const int lane = tid & 63;
    const int qd   = tid >> 6;          // wave id = channel quarter
    const int n0   = blockIdx.x * 64;
    const int n    = n0 + lane;

    if (qd == 0) {
        unsigned long long v = packedS[n];
        #pragma unroll
        for (int s = 1; s < SPLITS; ++s) {
            unsigned long long q = packedS[(size_t)s * N_PTS + n];
            v = (q < v) ? q : v;
        }
        int idx = (int)(v & 0xFFFFFFFFull);
        sidx[lane] = idx;
        out[QOUT_N + 2 + n] = (float)idx;
    }
    __syncthreads();

    const int idx = sidx[lane];
    const int c0  = qd * 16;
    const int b   = n >> 10;
    const int hw  = n & 1023;
    const float* xb = x   + (size_t)b * (C_DIM * HWSZ) + hw;
    float*       ob = out + (size_t)b * (C_DIM * HWSZ) + hw;

    float s = 0.0f;
    #pragma unroll
    for (int c4 = 0; c4 < 4; ++c4) {
        float4 q = *(const float4*)(cb + (size_t)idx * C_DIM + c0 + c4 * 4);
        float qa[4] = {q.x, q.y, q.z, q.w};
        #pragma unroll
        for (int j = 0; j < 4; ++j) {
            int c = c0 + c4 * 4 + j;
            float xv = xb[c * HWSZ];
            float d  = qa[j] - xv;          // quant - x (reference rounding)
            s = fmaf(d, d, s);
            ob[c * HWSZ] = xv + d;          // straight-through: x + (q - x)
        }
    }

    #pragma unroll
    for (int off = 32; off > 0; off >>= 1) s += __shfl_down(s, off, 64);
    if (lane == 0) part[blockIdx.x * 4 + qd] = s;
}

// ============================================================
// Kernel D: final loss reduction (512 partials -> 2 scalars).
// ============================================================
__global__ __launch_bounds__(256)
void vq_final_kernel(const float* __restrict__ part, float* __restrict__ out)
{
    __shared__ float w[4];
    float s = part[threadIdx.x] + part[threadIdx.x + 256];
    #pragma unroll
    for (int off = 32; off > 0; off >>= 1) s += __shfl_down(s, off, 64);
    if ((threadIdx.x & 63) == 0) w[threadIdx.x >> 6] = s;
    __syncthreads();
    if (threadIdx.x == 0) {
        float m = (w[0] + w[1] + w[2] + w[3]) * (1.0f / (float)QOUT_N);
        out[QOUT_N]     = m;   // commitment_loss
        out[QOUT_N + 1] = m;   // codebook_loss
    }
}

extern "C" void kernel_launch(void* const* d_in, const int* in_sizes, int n_in,
                              void* d_out, int out_size, void* d_ws, size_t ws_size,
                              hipStream_t stream)
{
    const float* x  = (const float*)d_in[0];   // [8,64,32,32]
    const float* cb = (const float*)d_in[1];   // [8192,64]
    float* out = (float*)d_out;
    char*  ws  = (char*)d_ws;
    (void)ws_size;

    unsigned short* xS  = (unsigned short*)(ws + WS_XS);
    unsigned short* cbS = (unsigned short*)(ws + WS_CBS);
    float* e2h = (float*)(ws + WS_E2H);
    unsigned long long* packedS = (unsigned long long*)(ws + WS_PACK);
    float* part = (float*)(ws + WS_PART);

    vq_prep_kernel<<<96, 256, 0, stream>>>(x, cb, xS, cbS, e2h);
    vq_argmin_kernel<<<dim3(N_PTS / 256, SPLITS), 256, 0, stream>>>(xS, cbS, e2h, packedS);
    vq_gather_kernel<<<128, 256, 0, stream>>>(x, cb, packedS, out, part);
    vq_final_kernel<<<1, 256, 0, stream>>>(part, out);
}